// Round 8
// baseline (242.042 us; speedup 1.0000x reference)
//
#include <hip/hip_runtime.h>
#include <hip/hip_bf16.h>

#define DIM 64

typedef __attribute__((ext_vector_type(4)))  float f32x4;
typedef __attribute__((ext_vector_type(8)))  short short8;
typedef __attribute__((ext_vector_type(4)))  unsigned short u16x4;
typedef __attribute__((ext_vector_type(2)))  unsigned int u32x2;

// ---------- wave helpers (wave64) ----------
static __device__ __forceinline__ float wave_sum64(float v) {
    v += __shfl_xor(v, 1, 64);
    v += __shfl_xor(v, 2, 64);
    v += __shfl_xor(v, 4, 64);
    v += __shfl_xor(v, 8, 64);
    v += __shfl_xor(v, 16, 64);
    v += __shfl_xor(v, 32, 64);
    return v;
}

static __device__ __forceinline__ float b2f(unsigned short u) {
    return __uint_as_float(((unsigned int)u) << 16);
}
static __device__ __forceinline__ unsigned short f2b(float f) {
    unsigned int u = __float_as_uint(f);
    unsigned int rounded = u + 0x7fff + ((u >> 16) & 1);
    return (unsigned short)(rounded >> 16);
}
static __device__ __forceinline__ float b2f_lo(unsigned int u) {
    return __uint_as_float(u << 16);
}
static __device__ __forceinline__ float b2f_hi(unsigned int u) {
    return __uint_as_float(u & 0xffff0000u);
}

// ---------- CSR build ----------
__global__ void k_hist(const int* __restrict__ dst, int* __restrict__ cnt, int E) {
    int e = blockIdx.x * blockDim.x + threadIdx.x;
    if (e < E) atomicAdd(&cnt[dst[e]], 1);
}

__global__ __launch_bounds__(1024) void k_scan1(const int* __restrict__ cnt,
                                                int* __restrict__ partial,
                                                int* __restrict__ blocksum, int n) {
    __shared__ int buf[1024];
    int t = threadIdx.x;
    int i = blockIdx.x * 1024 + t;
    int v = (i < n) ? cnt[i] : 0;
    buf[t] = v;
    __syncthreads();
    for (int off = 1; off < 1024; off <<= 1) {
        int x = (t >= off) ? buf[t - off] : 0;
        __syncthreads();
        buf[t] += x;
        __syncthreads();
    }
    if (i < n) partial[i] = buf[t];
    if (t == 1023) blocksum[blockIdx.x] = buf[1023];
}

__global__ __launch_bounds__(1024) void k_scan2(int* __restrict__ blocksum, int nb) {
    __shared__ int buf[1024];
    int t = threadIdx.x;
    buf[t] = (t < nb) ? blocksum[t] : 0;
    __syncthreads();
    for (int off = 1; off < 1024; off <<= 1) {
        int x = (t >= off) ? buf[t - off] : 0;
        __syncthreads();
        buf[t] += x;
        __syncthreads();
    }
    if (t < nb) blocksum[t] = buf[t];
}

__global__ void k_scan3(const int* __restrict__ partial, const int* __restrict__ blocksum,
                        const int* __restrict__ cnt,
                        int* __restrict__ row_start, int* __restrict__ cursor, int n) {
    int i = blockIdx.x * blockDim.x + threadIdx.x;
    if (i == 0) row_start[0] = 0;
    if (i < n) {
        int b = i >> 10;
        int add = (b > 0) ? blocksum[b - 1] : 0;
        int incl = partial[i] + add;
        row_start[i + 1] = incl;
        cursor[i] = incl - cnt[i];
    }
}

__global__ void k_fill(const int* __restrict__ src, const int* __restrict__ dst,
                       int* __restrict__ cursor, int* __restrict__ csr_src, int E) {
    int e = blockIdx.x * blockDim.x + threadIdx.x;
    if (e < E) {
        int p = atomicAdd(&cursor[dst[e]], 1);
        csr_src[p] = src[e];
    }
}

// ---------- W pre-convert: f32 -> bf16 hi/lo planes ----------
__global__ void k_wconv(const float* __restrict__ We, const float* __restrict__ Wb,
                        const float* __restrict__ Ws, unsigned short* __restrict__ wcvt,
                        int L) {
    int i = blockIdx.x * blockDim.x + threadIdx.x;
    int total = L * 3 * 4096;
    if (i >= total) return;
    int pos  = i & 4095;
    int lm   = i >> 12;          // l*3 + mode
    int mode = lm % 3;
    int l    = lm / 3;
    const float* W = (mode == 0) ? We : (mode == 1) ? Wb : Ws;
    float v = W[(size_t)l * 4096 + pos];
    unsigned short hi = f2b(v);
    unsigned short lo = f2b(v - b2f(hi));
    wcvt[((size_t)lm * 2 + 0) * 4096 + pos] = hi;
    wcvt[((size_t)lm * 2 + 1) * 4096 + pos] = lo;
}

// ---------- Phase A via MFMA, grid-stride tiles, packed stores ----------
// hb column order within a mode is PERMUTED: packed col c = 4*mrow + t holds
// feature f = 16*t + mrow. Aggregation commutes; phaseB un-permutes.
__global__ __launch_bounds__(256) void k_phaseA_mfma(
        const float* __restrict__ Xe, const float* __restrict__ Xb, const float* __restrict__ Xs,
        const unsigned short* __restrict__ wcvt,
        const float* __restrict__ be, const float* __restrict__ bb, const float* __restrict__ bs,
        unsigned short* __restrict__ hb, const float* __restrict__ curv,
        int n, int ntiles, int wavesPerMode) {
    int gtid = blockIdx.x * blockDim.x + threadIdx.x;
    int gw   = gtid >> 6;
    int lane = gtid & 63;
    int mode = gw / wavesPerMode;
    if (mode >= 3) return;
    int w0   = gw - mode * wavesPerMode;

    int mrow  = lane & 15;
    int half  = lane >> 4;

    const float* X    = (mode == 0) ? Xe : (mode == 1) ? Xb : Xs;
    const float* bias = (mode == 0) ? be : (mode == 1) ? bb : bs;
    float sc = sqrtf(curv[0]);

    const unsigned short* whi = wcvt + ((size_t)mode * 2 + 0) * 4096;
    const unsigned short* wlo = wcvt + ((size_t)mode * 2 + 1) * 4096;
    short8 b_hi[4][2], b_lo[4][2];
#pragma unroll
    for (int t = 0; t < 4; ++t) {
        int wrow = 16 * t + mrow;
#pragma unroll
        for (int kc = 0; kc < 2; ++kc) {
            int off = wrow * DIM + 32 * kc + 8 * half;
            b_hi[t][kc] = *reinterpret_cast<const short8*>(whi + off);
            b_lo[t][kc] = *reinterpret_cast<const short8*>(wlo + off);
        }
    }
    float bl[4];
#pragma unroll
    for (int t = 0; t < 4; ++t) bl[t] = bias[16 * t + mrow];

    for (int tile = w0; tile < ntiles; tile += wavesPerMode) {
        int node0 = tile * 16;
        int row = node0 + mrow;
        int rowc = (row < n) ? row : (n - 1);
        const float* xp = X + (size_t)rowc * DIM + 8 * half;
        float xv[16];
        {
            const float4* p0 = reinterpret_cast<const float4*>(xp);
            const float4* p1 = reinterpret_cast<const float4*>(xp + 32);
            float4 a = p0[0], b = p0[1], c = p1[0], d = p1[1];
            xv[0]=a.x; xv[1]=a.y; xv[2]=a.z; xv[3]=a.w;
            xv[4]=b.x; xv[5]=b.y; xv[6]=b.z; xv[7]=b.w;
            xv[8]=c.x; xv[9]=c.y; xv[10]=c.z; xv[11]=c.w;
            xv[12]=d.x; xv[13]=d.y; xv[14]=d.z; xv[15]=d.w;
        }

        float scale = 1.0f;
        if (mode != 0) {
            float ss = 0.f;
#pragma unroll
            for (int i = 0; i < 16; ++i) ss = fmaf(xv[i], xv[i], ss);
            ss += __shfl_xor(ss, 16, 64);
            ss += __shfl_xor(ss, 32, 64);
            if (mode == 1) {
                float dn = fmaxf(sqrtf(ss), 1e-10f);
                scale = (2.0f / sc) * atanhf(sc * dn) / dn;
            } else {
                float dn = fmaxf(sqrtf(ss), 1e-12f);
                scale = 1.0f / dn;
            }
        }

        short8 a_hi0, a_hi1, a_lo0, a_lo1;
#pragma unroll
        for (int i = 0; i < 8; ++i) {
            float s0 = xv[i] * scale;
            unsigned short h0 = f2b(s0);
            a_hi0[i] = (short)h0;
            a_lo0[i] = (short)f2b(s0 - b2f(h0));
            float s1 = xv[8 + i] * scale;
            unsigned short h1 = f2b(s1);
            a_hi1[i] = (short)h1;
            a_lo1[i] = (short)f2b(s1 - b2f(h1));
        }

        f32x4 acc[4];
#pragma unroll
        for (int t = 0; t < 4; ++t) {
            f32x4 a = {0.f, 0.f, 0.f, 0.f};
            a = __builtin_amdgcn_mfma_f32_16x16x32_bf16(a_hi0, b_hi[t][0], a, 0, 0, 0);
            a = __builtin_amdgcn_mfma_f32_16x16x32_bf16(a_hi1, b_hi[t][1], a, 0, 0, 0);
            a = __builtin_amdgcn_mfma_f32_16x16x32_bf16(a_lo0, b_hi[t][0], a, 0, 0, 0);
            a = __builtin_amdgcn_mfma_f32_16x16x32_bf16(a_lo1, b_hi[t][1], a, 0, 0, 0);
            a = __builtin_amdgcn_mfma_f32_16x16x32_bf16(a_hi0, b_lo[t][0], a, 0, 0, 0);
            a = __builtin_amdgcn_mfma_f32_16x16x32_bf16(a_hi1, b_lo[t][1], a, 0, 0, 0);
            acc[t] = a;
        }

        float v[4][4];
#pragma unroll
        for (int t = 0; t < 4; ++t) {
#pragma unroll
            for (int r = 0; r < 4; ++r) v[t][r] = acc[t][r] + bl[t];
        }

        if (mode == 2) {
#pragma unroll
            for (int r = 0; r < 4; ++r) {
                float s = v[0][r]*v[0][r] + v[1][r]*v[1][r] + v[2][r]*v[2][r] + v[3][r]*v[3][r];
                s += __shfl_xor(s, 1, 64);
                s += __shfl_xor(s, 2, 64);
                s += __shfl_xor(s, 4, 64);
                s += __shfl_xor(s, 8, 64);
                float inv = 1.0f / fmaxf(sqrtf(s), 1e-12f);
#pragma unroll
                for (int t = 0; t < 4; ++t) v[t][r] *= inv;
            }
        }

#pragma unroll
        for (int r = 0; r < 4; ++r) {
            int orow = node0 + half * 4 + r;
            if (orow < n) {
                u16x4 pk;
                pk.x = f2b(v[0][r]); pk.y = f2b(v[1][r]);
                pk.z = f2b(v[2][r]); pk.w = f2b(v[3][r]);
                *reinterpret_cast<u16x4*>(hb + (size_t)orow * 192 + mode * 64 + 4 * mrow) = pk;
            }
        }
    }
}

// ---------- Phase B: asm-forced 16 gathers in flight, LDS redistribute ----------
// One global_load_dwordx2 per edge; addresses built SALU-side from readlane'd
// indices; all 16 issue before a single vmcnt(0).
#define GL(i, gname, vt) \
    "v_readlane_b32 %[st], %[idx], " #i "\n\t" \
    "s_mul_i32 %[st], %[st], 384\n\t" \
    "v_add_u32 %[" vt "], %[st], %[lo]\n\t" \
    "global_load_dwordx2 %[" gname "], %[" vt "], %[bs]\n\t"

#define ACC(gi, i) { \
    float m = (j + i < end) ? 1.0f : 0.0f; \
    a0 = fmaf(b2f_lo(gi.x), m, a0); \
    a1 = fmaf(b2f_hi(gi.x), m, a1); \
    a2 = fmaf(b2f_lo(gi.y), m, a2); \
    a3 = fmaf(b2f_hi(gi.y), m, a3); }

__global__ __launch_bounds__(256) void k_phaseB(const unsigned short* __restrict__ hb,
                                                const int* __restrict__ row_start,
                                                const int* __restrict__ csr_src,
                                                float* __restrict__ e_out,
                                                float* __restrict__ b_out,
                                                float* __restrict__ s_out,
                                                const float* __restrict__ curv,
                                                int n) {
    __shared__ float smem[4][192];
    int gtid = blockIdx.x * blockDim.x + threadIdx.x;
    int wid  = gtid >> 6;
    int lane = threadIdx.x & 63;
    int w    = threadIdx.x >> 6;
    if (wid >= n) return;

    int beg = row_start[wid];
    int end = row_start[wid + 1];

    const void* hbp = (const void*)hb;
    unsigned int lane_off = (unsigned int)lane * 8u;   // lanes 0..47 cover 384B row
    bool active = lane < 48;

    float a0 = 0.f, a1 = 0.f, a2 = 0.f, a3 = 0.f;

    if (active) {
        for (int j = beg; j < end; j += 16) {
            int li = j + (lane & 15);
            li = (li < end) ? li : (end - 1);
            unsigned int idxv = (unsigned int)csr_src[li];

            u32x2 g0, g1, g2, g3, g4, g5, g6, g7;
            u32x2 g8, g9, g10, g11, g12, g13, g14, g15;
            unsigned int st, vt0, vt1;
            asm volatile(
                GL(0,  "g0",  "vt0") GL(1,  "g1",  "vt1")
                GL(2,  "g2",  "vt0") GL(3,  "g3",  "vt1")
                GL(4,  "g4",  "vt0") GL(5,  "g5",  "vt1")
                GL(6,  "g6",  "vt0") GL(7,  "g7",  "vt1")
                GL(8,  "g8",  "vt0") GL(9,  "g9",  "vt1")
                GL(10, "g10", "vt0") GL(11, "g11", "vt1")
                GL(12, "g12", "vt0") GL(13, "g13", "vt1")
                GL(14, "g14", "vt0") GL(15, "g15", "vt1")
                : [g0]"=&v"(g0),  [g1]"=&v"(g1),  [g2]"=&v"(g2),  [g3]"=&v"(g3),
                  [g4]"=&v"(g4),  [g5]"=&v"(g5),  [g6]"=&v"(g6),  [g7]"=&v"(g7),
                  [g8]"=&v"(g8),  [g9]"=&v"(g9),  [g10]"=&v"(g10),[g11]"=&v"(g11),
                  [g12]"=&v"(g12),[g13]"=&v"(g13),[g14]"=&v"(g14),[g15]"=&v"(g15),
                  [st]"=&s"(st), [vt0]"=&v"(vt0), [vt1]"=&v"(vt1)
                : [idx]"v"(idxv), [lo]"v"(lane_off), [bs]"s"(hbp)
                : "memory");
            asm volatile("s_waitcnt vmcnt(0)" ::: "memory");
            __builtin_amdgcn_sched_barrier(0);

            ACC(g0, 0)  ACC(g1, 1)  ACC(g2, 2)  ACC(g3, 3)
            ACC(g4, 4)  ACC(g5, 5)  ACC(g6, 6)  ACC(g7, 7)
            ACC(g8, 8)  ACC(g9, 9)  ACC(g10, 10) ACC(g11, 11)
            ACC(g12, 12) ACC(g13, 13) ACC(g14, 14) ACC(g15, 15)
        }
        smem[w][4 * lane + 0] = a0;
        smem[w][4 * lane + 1] = a1;
        smem[w][4 * lane + 2] = a2;
        smem[w][4 * lane + 3] = a3;
    }
    // wave-local LDS fence (no cross-wave dependency -> no barrier needed)
    asm volatile("s_waitcnt lgkmcnt(0)" ::: "memory");

    // un-permute: packed col c holds feature f=16*(c&3)+(c>>2); c(f)=4*(f&15)+(f>>4)
    int c = 4 * (lane & 15) + (lane >> 4);
    float fe = smem[w][c];
    float fb = smem[w][64 + c];
    float fs = smem[w][128 + c];

    int cnt = end - beg;
    float inv = 1.0f / (float)(cnt > 0 ? cnt : 1);
    fe *= inv; fb *= inv; fs *= inv;

    e_out[(size_t)wid * DIM + lane] = (fe >= 0.f) ? fe : 0.2f * fe;

    float cc = curv[0];
    float sc = sqrtf(cc);
    float vn = fmaxf(sqrtf(wave_sum64(fb * fb)), 1e-10f);
    float scale = tanhf(sc * vn * 0.5f) / (sc * vn);
    b_out[(size_t)wid * DIM + lane] = fb * scale;

    float nr = fmaxf(sqrtf(wave_sum64(fs * fs)), 1e-12f);
    s_out[(size_t)wid * DIM + lane] = fs / nr;
}

extern "C" void kernel_launch(void* const* d_in, const int* in_sizes, int n_in,
                              void* d_out, int out_size, void* d_ws, size_t ws_size,
                              hipStream_t stream) {
    const float* e0   = (const float*)d_in[0];
    const float* b0   = (const float*)d_in[1];
    const float* s0   = (const float*)d_in[2];
    const float* We   = (const float*)d_in[3];
    const float* be   = (const float*)d_in[4];
    const float* Wb   = (const float*)d_in[5];
    const float* bb   = (const float*)d_in[6];
    const float* Ws   = (const float*)d_in[7];
    const float* bs   = (const float*)d_in[8];
    const float* bcur = (const float*)d_in[9];
    const int*   src  = (const int*)d_in[11];
    const int*   dst  = (const int*)d_in[12];

    const int N = in_sizes[0] / DIM;
    const int E = in_sizes[11];
    const int L = in_sizes[3] / (DIM * DIM);

    // workspace carve
    const int Npad = (N + 1023) & ~1023;
    int* cnt       = (int*)d_ws;                  // Npad
    int* row_start = cnt + Npad;                  // Npad+64
    int* cursor    = row_start + Npad + 64;       // Npad (reused as `partial`)
    int* blocksum  = cursor + Npad;               // 1024
    int* csr_src   = blocksum + 1024;             // E
    unsigned short* hb   = (unsigned short*)(csr_src + ((E + 63) & ~63));   // N*192 bf16
    unsigned short* wcvt = hb + (size_t)N * 192;  // L*3*2*4096 bf16

    float* out_e = (float*)d_out;
    float* out_b = out_e + (size_t)N * DIM;
    float* out_s = out_b + (size_t)N * DIM;

    // ---- build CSR + W convert (once per call) ----
    hipMemsetAsync(cnt, 0, (size_t)N * sizeof(int), stream);
    {
        int blk = 256, grd = (E + blk - 1) / blk;
        k_hist<<<grd, blk, 0, stream>>>(dst, cnt, E);
        int nb = (N + 1023) / 1024;
        k_scan1<<<nb, 1024, 0, stream>>>(cnt, cursor /*partial*/, blocksum, N);
        k_scan2<<<1, 1024, 0, stream>>>(blocksum, nb);
        k_scan3<<<(N + 255) / 256, 256, 0, stream>>>(cursor /*partial*/, blocksum, cnt,
                                                     row_start, cursor, N);
        k_fill<<<grd, blk, 0, stream>>>(src, dst, cursor, csr_src, E);

        int wtot = L * 3 * 4096;
        k_wconv<<<(wtot + 255) / 256, 256, 0, stream>>>(We, Wb, Ws, wcvt, L);
    }

    const int ntiles = (N + 15) / 16;
    const int wavesPerMode = 1024;
    const int grdA   = (3 * wavesPerMode) / 4;     // 4 waves per 256-thr block
    const int grdB   = (N * DIM + 255) / 256;      // one wave per node

    for (int l = 0; l < L; ++l) {
        const float* Xe = (l == 0) ? e0 : out_e;
        const float* Xb = (l == 0) ? b0 : out_b;
        const float* Xs = (l == 0) ? s0 : out_s;

        k_phaseA_mfma<<<grdA, 256, 0, stream>>>(
            Xe, Xb, Xs,
            wcvt + (size_t)l * 3 * 2 * 4096,
            be + (size_t)l * DIM, bb + (size_t)l * DIM, bs + (size_t)l * DIM,
            hb, bcur, N, ntiles, wavesPerMode);

        k_phaseB<<<grdB, 256, 0, stream>>>(hb, row_start, csr_src,
                                           out_e, out_b, out_s, bcur, N);
    }
}